// Round 3
// baseline (438.468 us; speedup 1.0000x reference)
//
#include <hip/hip_runtime.h>
#include <math.h>

static constexpr int B_ = 32;
static constexpr int RES_ = 50;
static constexpr int F_ = 256;              // fine grid
#define NF (1.0f/(2.0f*0.05f*0.05f + 1e-8f))

// ---------------------------------------------------------------------------
// K-1: zero hs + T (float4 stores)
// ---------------------------------------------------------------------------
__global__ void __launch_bounds__(256) k_zero(float4* __restrict__ p, int n4) {
    int i = blockIdx.x * 256 + threadIdx.x;
    if (i < n4) p[i] = make_float4(0.f, 0.f, 0.f, 0.f);
}

// ---------------------------------------------------------------------------
// K0: Gaussian table in padded-slot layout gtab[c][slot], slot = w*16+k maps
//     to grid row i = w*13+k (k<13, i<50); other slots are 0.
// ---------------------------------------------------------------------------
__global__ void k_tables(float* __restrict__ gtab) {
    int c = blockIdx.x;                     // 0..255
    int s = threadIdx.x;                    // 0..63
    int w = s >> 4, k = s & 15;
    int i = w * 13 + k;
    float v = 0.0f;
    if (k < 13 && i < RES_) {
        float t = (float)i * (1.0f / 49.0f) - (float)c * (1.0f / 255.0f);
        v = __expf(-t * t * NF);
    }
    gtab[c * 64 + s] = v;
}

// ---------------------------------------------------------------------------
// K1: bilinear splat via device-scope fp32 atomics straight into hs[b][cx][cy].
//     2048 blocks x 256 threads, no LDS -> full occupancy. 8.4M atomics total,
//     ~4 adds/bin (uniform points) -> negligible contention.
// ---------------------------------------------------------------------------
__global__ void __launch_bounds__(256) k_splat(const float4* __restrict__ pts,
                                               float* __restrict__ hs,
                                               int nq_total, int nq_per_b) {
    int stride = gridDim.x * 256;
    for (int t = blockIdx.x * 256 + threadIdx.x; t < nq_total; t += stride) {
        float4 q = pts[t];
        int b = t / nq_per_b;
        float* hb = hs + ((size_t)b << 16);
#pragma unroll
        for (int h = 0; h < 2; h++) {
            float bx = h ? q.z : q.x;
            float dy = h ? q.w : q.y;
            float pers = fminf(fabsf(dy - bx), 10.0f);
            float wgt = pers * pers;
            float fx = fminf(fmaxf(bx * 255.0f, 0.0f), 255.0f);
            float fy = fminf(fmaxf(dy * 255.0f, 0.0f), 255.0f);
            int ix = (int)fx; if (ix > 254) ix = 254;
            int iy = (int)fy; if (iy > 254) iy = 254;
            float ax = fx - (float)ix;
            float ay = fy - (float)iy;
            float wx0 = wgt * (1.0f - ax), wx1 = wgt * ax;
            float a0 = 1.0f - ay;
            int o = (ix << 8) + iy;
            atomicAdd(hb + o,       wx0 * a0);
            atomicAdd(hb + o + 256, wx1 * a0);
            atomicAdd(hb + o + 1,   wx0 * ay);
            atomicAdd(hb + o + 257, wx1 * ay);
        }
    }
}

// ---------------------------------------------------------------------------
// K2: T[b][i][cy] += sum_{cx in quarter} gtab[cx][i] * hs[b][cx][cy]
//     512 blocks = (b, cxq, cyc); 4 waves row-split (13 rows each);
//     16 KB LDS table slice; accumulators flushed with atomicAdd into T.
// ---------------------------------------------------------------------------
__global__ void __launch_bounds__(256) k_conv1(const float* __restrict__ gtab,
                                               const float* __restrict__ hs,
                                               float* __restrict__ T) {
    __shared__ float sg[64 * 64];           // 16 KB: this block's cx-quarter
    int id = blockIdx.x;
    int cyc = id & 3;
    int cxq = (id >> 2) & 3;
    int b   = id >> 4;

    for (int t = threadIdx.x; t < 4096; t += 256)
        sg[t] = gtab[(cxq << 12) + t];
    __syncthreads();

    int tx = threadIdx.x & 63, ty = threadIdx.x >> 6;
    int cy = (cyc << 6) + tx;

    float acc[13];
#pragma unroll
    for (int k = 0; k < 13; k++) acc[k] = 0.0f;

    const float* hsb = hs + ((size_t)b << 16) + ((size_t)(cxq << 6) << 8) + cy;
    const float* gq = sg + (ty << 4);
#pragma unroll 8
    for (int c = 0; c < 64; c++) {
        float hv = hsb[(size_t)c << 8];
        const float* g = gq + (c << 6);
        float4 g0 = *(const float4*)(g);
        float4 g1 = *(const float4*)(g + 4);
        float4 g2 = *(const float4*)(g + 8);
        float  gc = g[12];
        acc[0]  += g0.x * hv;  acc[1]  += g0.y * hv;
        acc[2]  += g0.z * hv;  acc[3]  += g0.w * hv;
        acc[4]  += g1.x * hv;  acc[5]  += g1.y * hv;
        acc[6]  += g1.z * hv;  acc[7]  += g1.w * hv;
        acc[8]  += g2.x * hv;  acc[9]  += g2.y * hv;
        acc[10] += g2.z * hv;  acc[11] += g2.w * hv;
        acc[12] += gc * hv;
    }

    float* Tp = T + ((size_t)b * 52 + (size_t)ty * 13) * F_ + cy;
#pragma unroll
    for (int k = 0; k < 13; k++) atomicAdd(Tp + (size_t)k * F_, acc[k]);
}

// ---------------------------------------------------------------------------
// K3: out[b][i][j] = sum_cy T[b][i][cy] * gtab[cy][j]
// ---------------------------------------------------------------------------
__global__ void __launch_bounds__(256) k_conv2(const float* __restrict__ gtab,
                                               const float* __restrict__ T,
                                               float* __restrict__ out) {
    __shared__ float sT[13 * 256];          // 13 KB, reused as red[4][13][64]
    int q = blockIdx.x & 3;
    int b = blockIdx.x >> 2;

    const float* Tq = T + ((size_t)b * 52 + (size_t)q * 13) * F_;
    for (int t = threadIdx.x; t < 13 * 256; t += 256) sT[t] = Tq[t];
    __syncthreads();

    int j = threadIdx.x & 63;
    int w = threadIdx.x >> 6;
    int jc = j < RES_ ? j : RES_ - 1;
    int jo = (jc / 13) * 16 + (jc % 13);    // padded-slot column for output j

    float acc[13];
#pragma unroll
    for (int k = 0; k < 13; k++) acc[k] = 0.0f;

    const float* gp = gtab + jo + (size_t)w * 64 * 64;
    int cyb = w * 64;
#pragma unroll 4
    for (int c = 0; c < 64; c++) {
        float g = gp[(size_t)c * 64];
#pragma unroll
        for (int k = 0; k < 13; k++) acc[k] += sT[k * 256 + cyb + c] * g;
    }
    __syncthreads();

#pragma unroll
    for (int k = 0; k < 13; k++) sT[(w * 13 + k) * 64 + j] = acc[k];
    __syncthreads();

    for (int t = threadIdx.x; t < 13 * 64; t += 256) {
        int k = t >> 6, jj = t & 63;
        int i = q * 13 + k;
        if (i < RES_ && jj < RES_) {
            float s = sT[(0 * 13 + k) * 64 + jj] + sT[(1 * 13 + k) * 64 + jj]
                    + sT[(2 * 13 + k) * 64 + jj] + sT[(3 * 13 + k) * 64 + jj];
            out[((size_t)b * RES_ + i) * RES_ + jj] = s;
        }
    }
}

// ---------------------------------------------------------------------------
extern "C" void kernel_launch(void* const* d_in, const int* in_sizes, int n_in,
                              void* d_out, int out_size, void* d_ws, size_t ws_size,
                              hipStream_t stream) {
    const float4* pts = (const float4*)d_in[0];
    int N = in_sizes[0] / (2 * B_);         // 65536
    float* ws = (float*)d_ws;
    float* out = (float*)d_out;

    float* gtab = ws;                        // 16,384 floats (64 KB)
    float* hs   = gtab + F_ * 64;            // 32*256*256 = 2,097,152 floats
    float* T    = hs + (size_t)B_ * F_ * F_; // 32*52*256  =   425,984 floats

    // zero hs + T (contiguous)
    int zeroN4 = (B_ * F_ * F_ + B_ * 52 * F_) / 4;   // 630,784 float4
    k_zero<<<(zeroN4 + 255) / 256, 256, 0, stream>>>((float4*)hs, zeroN4);

    k_tables<<<F_, 64, 0, stream>>>(gtab);

    int nq_per_b = N >> 1;                   // float4 = 2 points
    int nq_total = B_ * nq_per_b;            // 1,048,576
    k_splat<<<2048, 256, 0, stream>>>(pts, hs, nq_total, nq_per_b);

    k_conv1<<<B_ * 16, 256, 0, stream>>>(gtab, hs, T);
    k_conv2<<<B_ * 4, 256, 0, stream>>>(gtab, T, out);
}

// Round 4
// 77.414 us; speedup vs baseline: 5.6640x; 5.6640x over previous
//
#include <hip/hip_runtime.h>
#include <math.h>

static constexpr int B_ = 32;
static constexpr int RES_ = 50;
static constexpr int F_ = 256;              // fine grid
#define NF (1.0f/(2.0f*0.05f*0.05f + 1e-8f))

// ---------------------------------------------------------------------------
// K0: Gaussian table, padded-slot layout gtab[c][slot]; slot = w*16+k maps to
//     grid row i = w*13+k (k<13, i<50); slots with k>=13 or i>=50 are 0.
// ---------------------------------------------------------------------------
__global__ void k_tables(float* __restrict__ gtab) {
    int c = blockIdx.x;                     // 0..255
    int s = threadIdx.x;                    // 0..63
    int w = s >> 4, k = s & 15;
    int i = w * 13 + k;
    float v = 0.0f;
    if (k < 13 && i < RES_) {
        float t = (float)i * (1.0f / 49.0f) - (float)c * (1.0f / 255.0f);
        v = __expf(-t * t * NF);
    }
    gtab[c * 64 + s] = v;
}

// ---------------------------------------------------------------------------
// K1: bilinear splat into private 64 KB LDS tile, plain full-tile store to
//     hs_part[p][b][cx][cy]. Grid 256 = (p,seg,b) with id%8 == b%8 so all 8
//     blocks of a batch share one XCD's L2 (points fetched from HBM once).
//     1024 threads = 16 waves -> 4 waves/SIMD for latency hiding.
// ---------------------------------------------------------------------------
__global__ void __launch_bounds__(1024) k_splat(const float4* __restrict__ pts,
                                                float* __restrict__ hs) {
    extern __shared__ float tile[];         // F_ * 64 floats = 64 KB
    int id  = blockIdx.x;
    int b   = id & 31;
    int seg = (id >> 5) & 3;
    int p   = id >> 7;                      // 0..1

    for (int t = threadIdx.x; t < F_ * 64; t += 1024) tile[t] = 0.0f;
    __syncthreads();

    int ylo = seg << 6;
    const float4* src = pts + ((size_t)b << 15) + ((size_t)p << 14);
    for (int t = threadIdx.x; t < 16384; t += 1024) {
        float4 q = src[t];
#pragma unroll
        for (int h = 0; h < 2; h++) {
            float bx = h ? q.z : q.x;
            float dy = h ? q.w : q.y;
            float pers = fminf(fabsf(dy - bx), 10.0f);
            float wgt = pers * pers;
            float fx = fminf(fmaxf(bx * 255.0f, 0.0f), 255.0f);
            float fy = fminf(fmaxf(dy * 255.0f, 0.0f), 255.0f);
            int ix = (int)fx; if (ix > 254) ix = 254;
            int iy = (int)fy; if (iy > 254) iy = 254;
            float ax = fx - (float)ix;
            float ay = fy - (float)iy;
            int cy0 = iy - ylo;
            float wx0 = wgt * (1.0f - ax), wx1 = wgt * ax;
            int o0 = (ix << 6) + cy0;
            if ((unsigned)cy0 < 64u) {
                float a0 = 1.0f - ay;
                atomicAdd(&tile[o0],      wx0 * a0);
                atomicAdd(&tile[o0 + 64], wx1 * a0);
            }
            if ((unsigned)(cy0 + 1) < 64u) {
                atomicAdd(&tile[o0 + 1],  wx0 * ay);
                atomicAdd(&tile[o0 + 65], wx1 * ay);
            }
        }
    }
    __syncthreads();

    float* dst = hs + (((size_t)p * B_ + b) << 16) + ylo;
    for (int t = threadIdx.x; t < F_ * 64; t += 1024)
        dst[(size_t)(t >> 6) * F_ + (t & 63)] = tile[t];
}

// ---------------------------------------------------------------------------
// K2: T_part[cxq][b][i][cy] = sum_{cx in quarter} gtab[cx][i] *
//                             (hs0[b][cx][cy] + hs1[b][cx][cy])
//     Grid 512 = (cxq,cyc,b) with id%8 == b%8 (hs stays in the batch's XCD
//     L2). Plain stores; rows 50,51 get zeros (zero table slots).
// ---------------------------------------------------------------------------
__global__ void __launch_bounds__(256) k_conv1(const float* __restrict__ gtab,
                                               const float* __restrict__ hs,
                                               float* __restrict__ T) {
    __shared__ float sg[64 * 64];           // 16 KB: this block's cx-quarter
    int id  = blockIdx.x;
    int b   = id & 31;
    int r   = id >> 5;
    int cyc = r & 3;
    int cxq = r >> 2;

    for (int t = threadIdx.x; t < 4096; t += 256)
        sg[t] = gtab[(cxq << 12) + t];
    __syncthreads();

    int tx = threadIdx.x & 63, ty = threadIdx.x >> 6;
    int cy = (cyc << 6) + tx;

    float acc[13];
#pragma unroll
    for (int k = 0; k < 13; k++) acc[k] = 0.0f;

    const float* h0 = hs + ((size_t)b << 16) + ((size_t)(cxq << 6) << 8) + cy;
    const float* h1 = h0 + ((size_t)B_ << 16);
    const float* gq = sg + (ty << 4);
#pragma unroll 4
    for (int c = 0; c < 64; c++) {
        float hv = h0[(size_t)c << 8] + h1[(size_t)c << 8];
        const float* g = gq + (c << 6);
        float4 g0 = *(const float4*)(g);
        float4 g1 = *(const float4*)(g + 4);
        float4 g2 = *(const float4*)(g + 8);
        float  gc = g[12];
        acc[0]  += g0.x * hv;  acc[1]  += g0.y * hv;
        acc[2]  += g0.z * hv;  acc[3]  += g0.w * hv;
        acc[4]  += g1.x * hv;  acc[5]  += g1.y * hv;
        acc[6]  += g1.z * hv;  acc[7]  += g1.w * hv;
        acc[8]  += g2.x * hv;  acc[9]  += g2.y * hv;
        acc[10] += g2.z * hv;  acc[11] += g2.w * hv;
        acc[12] += gc * hv;
    }

    float* Tp = T + (size_t)cxq * (B_ * 52 * F_)
                  + ((size_t)b * 52 + (size_t)ty * 13) * F_ + cy;
#pragma unroll
    for (int k = 0; k < 13; k++) Tp[(size_t)k * F_] = acc[k];
}

// ---------------------------------------------------------------------------
// K3: out[b][i][j] = sum_cy (sum_cxq T_part[cxq][b][i][cy]) * gtab[cy][j]
//     Grid 128 = (q,b), id%8 == b%8. Partial-sum during LDS staging.
// ---------------------------------------------------------------------------
__global__ void __launch_bounds__(256) k_conv2(const float* __restrict__ gtab,
                                               const float* __restrict__ T,
                                               float* __restrict__ out) {
    __shared__ float sT[13 * 256];          // 13 KB, reused as red[4][13][64]
    int b = blockIdx.x & 31;
    int q = blockIdx.x >> 5;

    const size_t TP = (size_t)B_ * 52 * F_;
    const float* Tq = T + ((size_t)b * 52 + (size_t)q * 13) * F_;
    for (int t = threadIdx.x; t < 13 * 256; t += 256)
        sT[t] = Tq[t] + Tq[TP + t] + Tq[2 * TP + t] + Tq[3 * TP + t];
    __syncthreads();

    int j = threadIdx.x & 63;
    int w = threadIdx.x >> 6;
    int jc = j < RES_ ? j : RES_ - 1;
    int jo = (jc / 13) * 16 + (jc % 13);    // padded-slot column for output j

    float acc[13];
#pragma unroll
    for (int k = 0; k < 13; k++) acc[k] = 0.0f;

    const float* gp = gtab + jo + (size_t)w * 64 * 64;
    int cyb = w * 64;
#pragma unroll 4
    for (int c = 0; c < 64; c++) {
        float g = gp[(size_t)c * 64];
#pragma unroll
        for (int k = 0; k < 13; k++) acc[k] += sT[k * 256 + cyb + c] * g;
    }
    __syncthreads();

#pragma unroll
    for (int k = 0; k < 13; k++) sT[(w * 13 + k) * 64 + j] = acc[k];
    __syncthreads();

    for (int t = threadIdx.x; t < 13 * 64; t += 256) {
        int k = t >> 6, jj = t & 63;
        int i = q * 13 + k;
        if (i < RES_ && jj < RES_) {
            float s = sT[(0 * 13 + k) * 64 + jj] + sT[(1 * 13 + k) * 64 + jj]
                    + sT[(2 * 13 + k) * 64 + jj] + sT[(3 * 13 + k) * 64 + jj];
            out[((size_t)b * RES_ + i) * RES_ + jj] = s;
        }
    }
}

// ---------------------------------------------------------------------------
extern "C" void kernel_launch(void* const* d_in, const int* in_sizes, int n_in,
                              void* d_out, int out_size, void* d_ws, size_t ws_size,
                              hipStream_t stream) {
    const float4* pts = (const float4*)d_in[0];
    float* ws = (float*)d_ws;
    float* out = (float*)d_out;

    float* gtab = ws;                         // 16,384 floats (64 KB)
    float* hs   = gtab + F_ * 64;             // 2 * 32*256*256 = 4,194,304 floats
    float* T    = hs + (size_t)2 * B_ * F_ * F_; // 4 * 32*52*256 = 1,703,936 floats
                                              // total ~23.7 MB (ws >= 43 MB proven R1)

    k_tables<<<F_, 64, 0, stream>>>(gtab);
    k_splat<<<256, 1024, (size_t)F_ * 64 * 4, stream>>>(pts, hs);
    k_conv1<<<512, 256, 0, stream>>>(gtab, hs, T);
    k_conv2<<<128, 256, 0, stream>>>(gtab, T, out);
}

// Round 5
// 73.621 us; speedup vs baseline: 5.9557x; 1.0515x over previous
//
#include <hip/hip_runtime.h>
#include <math.h>

static constexpr int B_ = 32;
static constexpr int RES_ = 50;
static constexpr int F_ = 256;              // fine grid
#define NF (1.0f/(2.0f*0.05f*0.05f + 1e-8f))

// ---------------------------------------------------------------------------
// K1: bilinear splat into private 64 KB LDS tile, float4 zero/store phases.
//     Grid 512 = (p:4, seg:4, b:32), id%8 == b%8 (XCD-sharded). 1024 thr =
//     16 waves; __launch_bounds__(1024,8) -> 2 blocks/CU co-resident ->
//     ALL 512 blocks resident at once; point chunks shared via XCD L2.
//     hs_part[p][b][cx][cy], plain stores, no zero-init needed.
// ---------------------------------------------------------------------------
__global__ void __launch_bounds__(1024, 8) k_splat(const float4* __restrict__ pts,
                                                   float* __restrict__ hs) {
    extern __shared__ float tile[];         // F_ * 64 floats = 64 KB
    int id  = blockIdx.x;
    int b   = id & 31;
    int seg = (id >> 5) & 3;
    int p   = id >> 7;                      // 0..3

    float4* t4 = (float4*)tile;
    for (int t = threadIdx.x; t < 4096; t += 1024)
        t4[t] = make_float4(0.f, 0.f, 0.f, 0.f);
    __syncthreads();

    int ylo = seg << 6;
    const float4* src = pts + ((size_t)b << 15) + ((size_t)p << 13);
    for (int t = threadIdx.x; t < 8192; t += 1024) {
        float4 q = src[t];
#pragma unroll
        for (int h = 0; h < 2; h++) {
            float bx = h ? q.z : q.x;
            float dy = h ? q.w : q.y;
            float pers = fminf(fabsf(dy - bx), 10.0f);
            float wgt = pers * pers;
            float fx = fminf(fmaxf(bx * 255.0f, 0.0f), 255.0f);
            float fy = fminf(fmaxf(dy * 255.0f, 0.0f), 255.0f);
            int ix = (int)fx; if (ix > 254) ix = 254;
            int iy = (int)fy; if (iy > 254) iy = 254;
            float ax = fx - (float)ix;
            float ay = fy - (float)iy;
            int cy0 = iy - ylo;
            float wx0 = wgt * (1.0f - ax), wx1 = wgt * ax;
            int o0 = (ix << 6) + cy0;
            if ((unsigned)cy0 < 64u) {
                float a0 = 1.0f - ay;
                atomicAdd(&tile[o0],      wx0 * a0);
                atomicAdd(&tile[o0 + 64], wx1 * a0);
            }
            if ((unsigned)(cy0 + 1) < 64u) {
                atomicAdd(&tile[o0 + 1],  wx0 * ay);
                atomicAdd(&tile[o0 + 65], wx1 * ay);
            }
        }
    }
    __syncthreads();

    // store: tile[cx][cyL] (float4 over cyL) -> hs[p][b][cx][ylo+cyL]
    float* dst = hs + (((size_t)p * B_ + b) << 16) + ylo;
    for (int t = threadIdx.x; t < 4096; t += 1024) {
        int cx = t >> 4, c4 = (t & 15) << 2;        // cyL quad
        *(float4*)(dst + (size_t)cx * F_ + c4) = t4[t];
    }
}

// ---------------------------------------------------------------------------
// K2: T_part[cxq][b][i][cy] = sum_{cx in quarter} G[cx][i] * sum_p hs[p][b][cx][cy]
//     Grid 512 = (cxq:4, cyc:4, b:32), id%8==b%8. Gaussian slice computed
//     in-kernel into 16 KB LDS (padded-slot layout: slot w*16+k -> row
//     i=w*13+k, k<13, i<50; else 0). 4 waves row-split; plain stores.
// ---------------------------------------------------------------------------
__global__ void __launch_bounds__(256, 4) k_conv1(const float* __restrict__ hs,
                                                  float* __restrict__ T) {
    __shared__ float sg[64 * 64];           // 16 KB
    int id  = blockIdx.x;
    int b   = id & 31;
    int r   = id >> 5;
    int cyc = r & 3;
    int cxq = r >> 2;

    for (int t = threadIdx.x; t < 4096; t += 256) {
        int cl = t >> 6, s = t & 63;
        int w = s >> 4, k = s & 15;
        int i = w * 13 + k;
        float v = 0.0f;
        if (k < 13 && i < RES_) {
            float d = (float)i * (1.0f / 49.0f)
                    - (float)((cxq << 6) + cl) * (1.0f / 255.0f);
            v = __expf(-d * d * NF);
        }
        sg[t] = v;
    }
    __syncthreads();

    int tx = threadIdx.x & 63, ty = threadIdx.x >> 6;
    int cy = (cyc << 6) + tx;

    float acc[13];
#pragma unroll
    for (int k = 0; k < 13; k++) acc[k] = 0.0f;

    const float* h0 = hs + ((size_t)b << 16) + ((size_t)(cxq << 6) << 8) + cy;
    const size_t PS = (size_t)B_ << 16;     // part stride
    const float* gq = sg + (ty << 4);
#pragma unroll 4
    for (int c = 0; c < 64; c++) {
        size_t o = (size_t)c << 8;
        float hv = h0[o] + h0[PS + o] + h0[2 * PS + o] + h0[3 * PS + o];
        const float* g = gq + (c << 6);
        float4 g0 = *(const float4*)(g);
        float4 g1 = *(const float4*)(g + 4);
        float4 g2 = *(const float4*)(g + 8);
        float  gc = g[12];
        acc[0]  += g0.x * hv;  acc[1]  += g0.y * hv;
        acc[2]  += g0.z * hv;  acc[3]  += g0.w * hv;
        acc[4]  += g1.x * hv;  acc[5]  += g1.y * hv;
        acc[6]  += g1.z * hv;  acc[7]  += g1.w * hv;
        acc[8]  += g2.x * hv;  acc[9]  += g2.y * hv;
        acc[10] += g2.z * hv;  acc[11] += g2.w * hv;
        acc[12] += gc * hv;
    }

    float* Tp = T + (size_t)cxq * ((size_t)B_ * 52 * F_)
                  + ((size_t)b * 52 + (size_t)ty * 13) * F_ + cy;
#pragma unroll
    for (int k = 0; k < 13; k++) Tp[(size_t)k * F_] = acc[k];
}

// ---------------------------------------------------------------------------
// K3: out[b][i][j] = sum_cy (sum_cxq T_part[cxq][b][i][cy]) * G[cy][j]
//     Grid 128 = (q:4, b:32), id%8==b%8. Gaussian computed inline (4 VALU +
//     1 trans per c-iter); T parts summed during LDS staging.
// ---------------------------------------------------------------------------
__global__ void __launch_bounds__(256) k_conv2(const float* __restrict__ T,
                                               float* __restrict__ out) {
    __shared__ float sT[13 * 256];          // 13 KB, reused as red[4][13][64]
    int b = blockIdx.x & 31;
    int q = blockIdx.x >> 5;

    const size_t TP = (size_t)B_ * 52 * F_;
    const float* Tq = T + ((size_t)b * 52 + (size_t)q * 13) * F_;
    for (int t = threadIdx.x; t < 13 * 256; t += 256)
        sT[t] = Tq[t] + Tq[TP + t] + Tq[2 * TP + t] + Tq[3 * TP + t];
    __syncthreads();

    int j = threadIdx.x & 63;
    int w = threadIdx.x >> 6;
    int jc = j < RES_ ? j : RES_ - 1;
    float xj = (float)jc * (1.0f / 49.0f);

    float acc[13];
#pragma unroll
    for (int k = 0; k < 13; k++) acc[k] = 0.0f;

    int cyb = w * 64;
#pragma unroll 4
    for (int c = 0; c < 64; c++) {
        float d = xj - (float)(cyb + c) * (1.0f / 255.0f);
        float g = __expf(-d * d * NF);
#pragma unroll
        for (int k = 0; k < 13; k++) acc[k] += sT[k * 256 + cyb + c] * g;
    }
    __syncthreads();

#pragma unroll
    for (int k = 0; k < 13; k++) sT[(w * 13 + k) * 64 + j] = acc[k];
    __syncthreads();

    for (int t = threadIdx.x; t < 13 * 64; t += 256) {
        int k = t >> 6, jj = t & 63;
        int i = q * 13 + k;
        if (i < RES_ && jj < RES_) {
            float s = sT[(0 * 13 + k) * 64 + jj] + sT[(1 * 13 + k) * 64 + jj]
                    + sT[(2 * 13 + k) * 64 + jj] + sT[(3 * 13 + k) * 64 + jj];
            out[((size_t)b * RES_ + i) * RES_ + jj] = s;
        }
    }
}

// ---------------------------------------------------------------------------
extern "C" void kernel_launch(void* const* d_in, const int* in_sizes, int n_in,
                              void* d_out, int out_size, void* d_ws, size_t ws_size,
                              hipStream_t stream) {
    const float4* pts = (const float4*)d_in[0];
    float* ws = (float*)d_ws;
    float* out = (float*)d_out;

    float* hs = ws;                           // 4 * 32*256*256 = 8,388,608 floats (33.6 MB)
    float* T  = hs + (size_t)4 * B_ * F_ * F_; // 4 * 32*52*256 = 1,703,936 floats (6.8 MB)
                                              // total ~40.4 MB (ws >= 43.7 MB proven R1)

    k_splat<<<512, 1024, (size_t)F_ * 64 * 4, stream>>>(pts, hs);
    k_conv1<<<512, 256, 0, stream>>>(hs, T);
    k_conv2<<<128, 256, 0, stream>>>(T, out);
}